// Round 5
// baseline (43.714 us; speedup 1.0000x reference)
//
#include <hip/hip_runtime.h>

// SeqMasking: right-align kept tokens (rand > 0.15), zero-fill left prefix.
// B=64, T=2048, D=256, fp32.
//
// R5: fused kernel, 32 rows/block (was 16) -> 4096 blocks, halving the
// redundant per-block keep-scan overhead. Each 256-thread block owns 32
// consecutive output rows of one batch, redundantly recomputes that batch's
// keep-scan into an LDS compaction map (smap[2048], 8 KB), then gathers.
// 64 blocks share each rand row -> re-reads are L2 hits. No inter-block
// communication (XCD-safe), deterministic.
//
// R2 lesson: __builtin_nontemporal_load/store cost +10us (45.6 -> 55.3).
// Plain loads/stores only.

#define P_DROP 0.15f

typedef float f32x4 __attribute__((ext_vector_type(4)));

__global__ __launch_bounds__(256)
void seqmask_fused_kernel(const float* __restrict__ x,
                          const float* __restrict__ rand,
                          float* __restrict__ out) {
    const int T = 2048, D = 256;
    const int b    = blockIdx.x >> 6;          // 64 blocks per batch
    const int j0   = (blockIdx.x & 63) << 5;   // 32 rows per block
    const int tid  = threadIdx.x;
    const int wave = tid >> 6;
    const int lane = tid & 63;

    __shared__ int smap[2048];   // compaction map: smap[k] = orig idx of k-th kept
    __shared__ int wsum[4];

    // ---- Phase 1: scan this batch's rand row (8 elems/thread, vectorized) ----
    const float* r = rand + (size_t)b * T + tid * 8;
    f32x4 r0 = *reinterpret_cast<const f32x4*>(r);
    f32x4 r1 = *reinterpret_cast<const f32x4*>(r + 4);

    int keep[8];
    keep[0] = r0.x > P_DROP; keep[1] = r0.y > P_DROP;
    keep[2] = r0.z > P_DROP; keep[3] = r0.w > P_DROP;
    keep[4] = r1.x > P_DROP; keep[5] = r1.y > P_DROP;
    keep[6] = r1.z > P_DROP; keep[7] = r1.w > P_DROP;

    int cnt = 0;
#pragma unroll
    for (int i = 0; i < 8; ++i) cnt += keep[i];

    int inc = cnt;                             // wave inclusive scan, no barrier
#pragma unroll
    for (int off = 1; off < 64; off <<= 1) {
        int n = __shfl_up(inc, off, 64);
        if (lane >= off) inc += n;
    }
    if (lane == 63) wsum[wave] = inc;
    __syncthreads();

    int wexcl = 0;
#pragma unroll
    for (int w = 0; w < 4; ++w) wexcl += (w < wave) ? wsum[w] : 0;
    const int l = wsum[0] + wsum[1] + wsum[2] + wsum[3];

    int pos = wexcl + inc - cnt;               // exclusive prefix for this thread
#pragma unroll
    for (int i = 0; i < 8; ++i) {
        if (keep[i]) smap[pos++] = tid * 8 + i;
    }
    __syncthreads();

    // ---- Phase 2: gather 32 rows (8 per wave), 1 KB per row ----
    const size_t xb = (size_t)b * T * D;
#pragma unroll
    for (int rr = 0; rr < 8; ++rr) {
        const int j = j0 + wave * 8 + rr;
        const int q = j - (T - l);
        f32x4 v = (f32x4)(0.f, 0.f, 0.f, 0.f);
        if (q >= 0) {
            const int st = smap[q];            // wave-uniform LDS broadcast
            v = *reinterpret_cast<const f32x4*>(x + xb + (size_t)st * D + lane * 4);
        }
        *reinterpret_cast<f32x4*>(out + xb + (size_t)j * D + lane * 4) = v;
    }
}

extern "C" void kernel_launch(void* const* d_in, const int* in_sizes, int n_in,
                              void* d_out, int out_size, void* d_ws, size_t ws_size,
                              hipStream_t stream) {
    const float* x    = (const float*)d_in[0];   // (B, T, D) fp32
    const float* rand = (const float*)d_in[1];   // (B, T)    fp32
    float* out        = (float*)d_out;

    const int BT = in_sizes[1];                  // B*T = 131072
    seqmask_fused_kernel<<<BT / 32, 256, 0, stream>>>(x, rand, out);
}

// Round 6
// 42.189 us; speedup vs baseline: 1.0361x; 1.0361x over previous
//
#include <hip/hip_runtime.h>

// SeqMasking: right-align kept tokens (rand > 0.15), zero-fill left prefix.
// B=64, T=2048, D=256, fp32.
//
// R6: back to 16 rows/block (R4 geometry, 8192 blocks — R5's 32-row variant
// was -0.8us) + explicit MLP in the gather: each wave loads its 4 rows into
// named registers FIRST (4 outstanding dwordx4 loads/lane), then stores.
// R5 counters showed VGPR_Count=12 -> compiler had serialized load/store
// per row (MLP=1); this forces MLP=4.
//
// R2 lesson: __builtin_nontemporal_load/store cost +10us. Plain ops only.

#define P_DROP 0.15f

typedef float f32x4 __attribute__((ext_vector_type(4)));

__global__ __launch_bounds__(256)
void seqmask_fused_kernel(const float* __restrict__ x,
                          const float* __restrict__ rand,
                          float* __restrict__ out) {
    const int T = 2048, D = 256;
    const int b    = blockIdx.x >> 7;          // 128 blocks per batch
    const int j0   = (blockIdx.x & 127) << 4;  // 16 rows per block
    const int tid  = threadIdx.x;
    const int wave = tid >> 6;
    const int lane = tid & 63;

    __shared__ int smap[2048];   // compaction map: smap[k] = orig idx of k-th kept
    __shared__ int wsum[4];

    // ---- Phase 1: scan this batch's rand row (8 elems/thread, vectorized) ----
    const float* r = rand + (size_t)b * T + tid * 8;
    f32x4 r0 = *reinterpret_cast<const f32x4*>(r);
    f32x4 r1 = *reinterpret_cast<const f32x4*>(r + 4);

    int keep[8];
    keep[0] = r0.x > P_DROP; keep[1] = r0.y > P_DROP;
    keep[2] = r0.z > P_DROP; keep[3] = r0.w > P_DROP;
    keep[4] = r1.x > P_DROP; keep[5] = r1.y > P_DROP;
    keep[6] = r1.z > P_DROP; keep[7] = r1.w > P_DROP;

    int cnt = 0;
#pragma unroll
    for (int i = 0; i < 8; ++i) cnt += keep[i];

    int inc = cnt;                             // wave inclusive scan, no barrier
#pragma unroll
    for (int off = 1; off < 64; off <<= 1) {
        int n = __shfl_up(inc, off, 64);
        if (lane >= off) inc += n;
    }
    if (lane == 63) wsum[wave] = inc;
    __syncthreads();

    int wexcl = 0;
#pragma unroll
    for (int w = 0; w < 4; ++w) wexcl += (w < wave) ? wsum[w] : 0;
    const int l = wsum[0] + wsum[1] + wsum[2] + wsum[3];

    int pos = wexcl + inc - cnt;               // exclusive prefix for this thread
#pragma unroll
    for (int i = 0; i < 8; ++i) {
        if (keep[i]) smap[pos++] = tid * 8 + i;
    }
    __syncthreads();

    // ---- Phase 2: gather 4 rows per wave — all loads first (MLP=4), then stores ----
    const size_t xb   = (size_t)b * T * D;
    const int jbase   = j0 + wave * 4;
    const int qbase   = jbase - (T - l);
    const float* xlb  = x + xb + lane * 4;

    f32x4 v0 = (f32x4)(0.f), v1 = (f32x4)(0.f), v2 = (f32x4)(0.f), v3 = (f32x4)(0.f);
    if (qbase + 0 >= 0) v0 = *reinterpret_cast<const f32x4*>(xlb + (size_t)smap[qbase + 0] * D);
    if (qbase + 1 >= 0) v1 = *reinterpret_cast<const f32x4*>(xlb + (size_t)smap[qbase + 1] * D);
    if (qbase + 2 >= 0) v2 = *reinterpret_cast<const f32x4*>(xlb + (size_t)smap[qbase + 2] * D);
    if (qbase + 3 >= 0) v3 = *reinterpret_cast<const f32x4*>(xlb + (size_t)smap[qbase + 3] * D);

    float* olb = out + xb + (size_t)jbase * D + lane * 4;
    *reinterpret_cast<f32x4*>(olb + 0 * D) = v0;
    *reinterpret_cast<f32x4*>(olb + 1 * D) = v1;
    *reinterpret_cast<f32x4*>(olb + 2 * D) = v2;
    *reinterpret_cast<f32x4*>(olb + 3 * D) = v3;
}

extern "C" void kernel_launch(void* const* d_in, const int* in_sizes, int n_in,
                              void* d_out, int out_size, void* d_ws, size_t ws_size,
                              hipStream_t stream) {
    const float* x    = (const float*)d_in[0];   // (B, T, D) fp32
    const float* rand = (const float*)d_in[1];   // (B, T)    fp32
    float* out        = (float*)d_out;

    const int BT = in_sizes[1];                  // B*T = 131072
    seqmask_fused_kernel<<<BT / 16, 256, 0, stream>>>(x, rand, out);
}